// Round 6
// baseline (1115.833 us; speedup 1.0000x reference)
//
#include <hip/hip_runtime.h>
#include <hip/hip_bf16.h>

#define EMBED  64
#define TLEN   256
#define BATCH  32
#define NROWS  (BATCH*TLEN)      // 8192
#define VOCAB  50257
#define SCOLS  512               // stripe width
#define NSTR   99                // stripes per row
#define VPAD   (NSTR*SCOLS)      // 50688, zero-padded B rows
#define LNEPS  1e-5f

typedef __attribute__((ext_vector_type(8))) short  bf16x8;
typedef __attribute__((ext_vector_type(4))) float  f32x4;
typedef __attribute__((ext_vector_type(4))) unsigned int u32x4;

static __device__ __forceinline__ unsigned short f2bf(float f) {
    unsigned int u = __float_as_uint(f);
    unsigned int r = (u + 0x7fffu + ((u >> 16) & 1u)) >> 16;   // RNE
    return (unsigned short)r;
}

// ---------------- fc_w [64][VOCAB] f32  ->  wt [VPAD][64] bf16 (transposed, zero-padded)
__global__ __launch_bounds__(256) void prep_wt(const float* __restrict__ fcw,
                                               unsigned short* __restrict__ wt) {
    int n = blockIdx.x * 256 + threadIdx.x;
    if (n >= VPAD) return;
    unsigned int packed[32];
    if (n < VOCAB) {
        #pragma unroll
        for (int k2 = 0; k2 < 32; ++k2) {
            unsigned int lo = f2bf(fcw[(size_t)(2*k2)   * VOCAB + n]);
            unsigned int hi = f2bf(fcw[(size_t)(2*k2+1) * VOCAB + n]);
            packed[k2] = lo | (hi << 16);
        }
    } else {
        #pragma unroll
        for (int k2 = 0; k2 < 32; ++k2) packed[k2] = 0u;
    }
    u32x4* dst = (u32x4*)(wt + (size_t)n * 64);
    #pragma unroll
    for (int i = 0; i < 8; ++i) {
        u32x4 v = { packed[4*i], packed[4*i+1], packed[4*i+2], packed[4*i+3] };
        dst[i] = v;
    }
}

// ---------------- embed gather + pos add -> h ; LN1 -> hn   (one wave per row)
__global__ __launch_bounds__(256) void embed_ln(const int* __restrict__ x,
                                                const float* __restrict__ ew,
                                                const float* __restrict__ pw,
                                                const float* __restrict__ g,
                                                const float* __restrict__ bb,
                                                float* __restrict__ h,
                                                float* __restrict__ hn) {
    int row = blockIdx.x * 4 + (threadIdx.x >> 6);
    int e   = threadIdx.x & 63;
    int tok = x[row];
    float v = ew[(size_t)tok * 64 + e] + pw[(size_t)(row & 255) * 64 + e];
    h[(size_t)row * 64 + e] = v;
    float s = v;
    #pragma unroll
    for (int m = 32; m >= 1; m >>= 1) s += __shfl_xor(s, m, 64);
    float mu = s * (1.f/64.f);
    float d  = v - mu;
    float s2 = d * d;
    #pragma unroll
    for (int m = 32; m >= 1; m >>= 1) s2 += __shfl_xor(s2, m, 64);
    float var = s2 * (1.f/64.f);
    hn[(size_t)row * 64 + e] = d * rsqrtf(var + LNEPS) * g[e] + bb[e];
}

// ---------------- Q,K,V GEMMs.  wave0->Q, wave1->K (stored transposed), wave2->V
__global__ __launch_bounds__(192) void qkv(const float* __restrict__ hn,
                                           const float* __restrict__ wq,
                                           const float* __restrict__ wk,
                                           const float* __restrict__ wv,
                                           float* __restrict__ q,
                                           float* __restrict__ kt,
                                           float* __restrict__ v) {
    int wave = threadIdx.x >> 6;     // 0..2
    int j    = threadIdx.x & 63;
    const float* W = (wave == 0) ? wq : ((wave == 1) ? wk : wv);
    int m0 = blockIdx.x * 16;
    for (int r = 0; r < 16; ++r) {
        int m = m0 + r;
        const float* hr = hn + (size_t)m * 64;   // uniform -> scalar loads
        float acc = 0.f;
        #pragma unroll
        for (int e = 0; e < 64; ++e) acc += hr[e] * W[e * 64 + j];
        if (wave == 0)      q[(size_t)m * 64 + j] = acc;
        else if (wave == 1) {
            int b = m >> 8, t = m & 255;
            kt[((size_t)b * 64 + j) * 256 + t] = acc;
        } else              v[(size_t)m * 64 + j] = acc;
    }
}

// ---------------- scores (QK^T/8, causal) + softmax -> P f32.  4 query rows per block.
__global__ __launch_bounds__(256) void attn_sm(const float* __restrict__ q,
                                               const float* __restrict__ kt,
                                               float* __restrict__ p) {
    int b   = blockIdx.y;            // 0..31
    int m4  = blockIdx.x;            // 0..63
    int key = threadIdx.x;           // 0..255
    int wave = key >> 6, lane = key & 63;
    const float* ktb = kt + (size_t)b * 64 * 256;
    const float* qb  = q  + ((size_t)b * 256 + m4 * 4) * 64;   // 4 rows, uniform
    float s0=0.f, s1=0.f, s2=0.f, s3=0.f;
    for (int e = 0; e < 64; ++e) {
        float kv = ktb[e * 256 + key];
        s0 += qb[e]       * kv;
        s1 += qb[64 + e]  * kv;
        s2 += qb[128 + e] * kv;
        s3 += qb[192 + e] * kv;
    }
    float sv[4] = { s0*0.125f, s1*0.125f, s2*0.125f, s3*0.125f };
    __shared__ float redm[4][4], reds[4][4];
    float pe[4];
    #pragma unroll
    for (int r = 0; r < 4; ++r) {
        int mrow = m4 * 4 + r;
        float xv = (key <= mrow) ? sv[r] : -1e30f;
        sv[r] = xv;
        float wm = xv;
        #pragma unroll
        for (int mm = 32; mm >= 1; mm >>= 1) wm = fmaxf(wm, __shfl_xor(wm, mm, 64));
        if (lane == 0) redm[wave][r] = wm;
    }
    __syncthreads();
    #pragma unroll
    for (int r = 0; r < 4; ++r) {
        float M = fmaxf(fmaxf(redm[0][r], redm[1][r]), fmaxf(redm[2][r], redm[3][r]));
        float e_ = expf(sv[r] - M);
        pe[r] = e_;
        float ws = e_;
        #pragma unroll
        for (int mm = 32; mm >= 1; mm >>= 1) ws += __shfl_xor(ws, mm, 64);
        if (lane == 0) reds[wave][r] = ws;
    }
    __syncthreads();
    float* pb = p + ((size_t)b * 256 + m4 * 4) * 256;
    #pragma unroll
    for (int r = 0; r < 4; ++r) {
        float S = reds[0][r] + reds[1][r] + reds[2][r] + reds[3][r];
        pb[r * 256 + key] = pe[r] / S;
    }
}

// ---------------- ctx = P@V ; h2 = h + ctx ; LNf -> hf bf16.  One wave per row.
__global__ __launch_bounds__(256) void ctx_lnf(const float* __restrict__ p,
                                               const float* __restrict__ v,
                                               const float* __restrict__ h,
                                               const float* __restrict__ g,
                                               const float* __restrict__ bb,
                                               unsigned short* __restrict__ hf) {
    int m = blockIdx.x * 4 + (threadIdx.x >> 6);
    int n = threadIdx.x & 63;
    int b = m >> 8, t = m & 255;
    const float* pr = p + ((size_t)b * 256 + t) * 256;   // uniform -> scalar loads
    const float* vb = v + (size_t)b * 256 * 64;
    float acc = 0.f;
    for (int key = 0; key <= t; ++key)
        acc += pr[key] * vb[key * 64 + n];
    float h2 = h[(size_t)m * 64 + n] + acc;
    float s = h2;
    #pragma unroll
    for (int mm = 32; mm >= 1; mm >>= 1) s += __shfl_xor(s, mm, 64);
    float mu = s * (1.f/64.f);
    float d  = h2 - mu;
    float s2 = d * d;
    #pragma unroll
    for (int mm = 32; mm >= 1; mm >>= 1) s2 += __shfl_xor(s2, mm, 64);
    float var = s2 * (1.f/64.f);
    hf[(size_t)m * 64 + n] = f2bf(d * rsqrtf(var + LNEPS) * g[n] + bb[n]);
}

// ---------------- logits = hf @ fc_w + fc_b  (bf16 MFMA, f32 out)
// Persistent drain-free pipeline: 512 blocks (1 per 16-row band, 2/CU, all
// co-resident). Each sweeps 99 x 512-col stripes with double-buffered LDS:
// compute stripe s+1 into buf^1 WHILE storing stripe s from buf. Barriers are
// raw s_barrier preceded only by s_waitcnt lgkmcnt(0) -> global stores are
// NEVER drained in the loop (the R5 mistake: __syncthreads emits vmcnt(0)).
// MFMA operands swapped (A=wt, B=hf) so each lane's c[0..3] = 4 consecutive
// vocab cols -> LDS fill is 8x ds_write_b128 (2-way bank alias, free).
// XCD-slab remap keeps each XCD's 64 blocks on one wt stripe (L2-hot).
__global__ __launch_bounds__(256, 2) void final_gemm(const unsigned short* __restrict__ hf,
                                                     const unsigned short* __restrict__ wt,
                                                     const float* __restrict__ bias,
                                                     float* __restrict__ out) {
    int bid = blockIdx.x;                 // 0..511
    int xcd = bid & 7;
    int mb  = xcd * 64 + (bid >> 3);      // band 0..511
    int m0  = mb * 16;

    int tid  = threadIdx.x;
    int wave = tid >> 6, lane = tid & 63;
    int l15 = lane & 15, lk = lane >> 4;

    __shared__ float lds[2][16][520];     // 66.6 KB -> 2 blocks/CU

    // B-operand (tokens): hf rows m0+l15, loaded once, reused for all stripes
    const bf16x8* hrow = (const bf16x8*)(hf + (size_t)(m0 + l15) * 64);
    bf16x8 hb0 = hrow[lk];       // k 0..31
    bf16x8 hb1 = hrow[4 + lk];   // k 32..63

    int srow = tid >> 4, scc = tid & 15;  // store map: 16 thr/row, 256B runs
    float* orow = out + (size_t)(m0 + srow) * VOCAB;

    // compute stripe s into lds[buf]: D[m=vocab][n=token]; lane (l15,lk) owns
    // token l15, vocab cols tile+lk*4..+3 -> one f32x4 ds_write per tile.
    auto computeS = [&](int s, int buf) {
        int cbase = s * SCOLS;
        #pragma unroll
        for (int nt = 0; nt < 8; ++nt) {
            int lcol = wave * 128 + nt * 16;          // tile base within stripe
            int wr   = cbase + lcol + l15;            // wt row for A-frag
            const bf16x8* wrow = (const bf16x8*)(wt + (size_t)wr * 64);
            f32x4 c = {0.f, 0.f, 0.f, 0.f};
            c = __builtin_amdgcn_mfma_f32_16x16x32_bf16(wrow[lk],     hb0, c, 0, 0, 0);
            c = __builtin_amdgcn_mfma_f32_16x16x32_bf16(wrow[4 + lk], hb1, c, 0, 0, 0);
            int bc = cbase + lcol + lk * 4;           // 4 consecutive vocab cols
            if (bc + 4 <= VOCAB) {
                f32x4 bv = *(const f32x4*)(bias + bc);
                c += bv;
            } else {
                #pragma unroll
                for (int e = 0; e < 4; ++e)
                    c[e] += (bc + e < VOCAB) ? bias[bc + e] : 0.f;
            }
            *(f32x4*)&lds[buf][l15][lcol + lk * 4] = c;
        }
    };

    auto storeS = [&](int s, int buf) {
        int cbase = s * SCOLS;
        const float* lrow = &lds[buf][srow][0];
        #pragma unroll
        for (int i = 0; i < 8; ++i) {
            int lcol = i * 64 + scc * 4;
            f32x4 vv = *(const f32x4*)(lrow + lcol);
            int cs = cbase + lcol;
            if (cs + 4 <= VOCAB) {
                *(f32x4*)(orow + cs) = vv;
            } else {
                #pragma unroll
                for (int e = 0; e < 4; ++e)
                    if (cs + e < VOCAB) orow[cs + e] = vv[e];
            }
        }
    };

    computeS(0, 0);
    int cur = 0;
    for (int s = 0; s < NSTR; ++s) {
        // own DS ops (buf writes from compute, buf^1 reads from prior store)
        // must land before the rendezvous; global stores stay in flight.
        asm volatile("s_waitcnt lgkmcnt(0)" ::: "memory");
        __builtin_amdgcn_s_barrier();
        __builtin_amdgcn_sched_barrier(0);
        if (s + 1 < NSTR) computeS(s + 1, cur ^ 1);
        storeS(s, cur);
        cur ^= 1;
    }
}

extern "C" void kernel_launch(void* const* d_in, const int* in_sizes, int n_in,
                              void* d_out, int out_size, void* d_ws, size_t ws_size,
                              hipStream_t stream) {
    const int*   x    = (const int*)  d_in[0];
    const float* ew   = (const float*)d_in[1];
    const float* pw   = (const float*)d_in[2];
    const float* ln1g = (const float*)d_in[3];
    const float* ln1b = (const float*)d_in[4];
    const float* wq   = (const float*)d_in[5];
    const float* wk   = (const float*)d_in[6];
    const float* wv   = (const float*)d_in[7];
    const float* lnfg = (const float*)d_in[8];
    const float* lnfb = (const float*)d_in[9];
    const float* fcw  = (const float*)d_in[10];
    const float* fcb  = (const float*)d_in[11];
    float* out = (float*)d_out;

    char* ws = (char*)d_ws;
    float*          h  = (float*)(ws + 0);                    //  0..2 MB
    float*          hn = (float*)(ws + (2u<<20));             //  2..4 MB (dead after qkv)
    unsigned short* hf = (unsigned short*)(ws + (2u<<20));    //  reuses hn slot (1 MB)
    float*          q  = (float*)(ws + (4u<<20));             //  4..6 MB
    float*          kt = (float*)(ws + (6u<<20));             //  6..8 MB
    float*          v  = (float*)(ws + (8u<<20));             //  8..10 MB
    float*          p  = (float*)(ws + (10u<<20));            // 10..18 MB
    unsigned short* wt = (unsigned short*)(ws + (18u<<20));   // 18..24.2 MB

    prep_wt  <<<dim3(VPAD / 256),  dim3(256), 0, stream>>>(fcw, wt);
    embed_ln <<<dim3(NROWS / 4),   dim3(256), 0, stream>>>(x, ew, pw, ln1g, ln1b, h, hn);
    qkv      <<<dim3(NROWS / 16),  dim3(192), 0, stream>>>(hn, wq, wk, wv, q, kt, v);
    attn_sm  <<<dim3(64, 32),      dim3(256), 0, stream>>>(q, kt, p);
    ctx_lnf  <<<dim3(NROWS / 4),   dim3(256), 0, stream>>>(p, v, h, lnfg, lnfb, hf);
    final_gemm<<<dim3(512),        dim3(256), 0, stream>>>(hf, wt, fcb, out);
}

// Round 7
// 1014.232 us; speedup vs baseline: 1.1002x; 1.1002x over previous
//
#include <hip/hip_runtime.h>
#include <hip/hip_bf16.h>

#define EMBED  64
#define TLEN   256
#define BATCH  32
#define NROWS  (BATCH*TLEN)      // 8192
#define VOCAB  50257
#define SCOLS  512               // stripe width
#define NSTR   99                // stripes per row
#define VPAD   (NSTR*SCOLS)      // 50688, zero-padded B rows
#define LNEPS  1e-5f

typedef __attribute__((ext_vector_type(8))) short  bf16x8;
typedef __attribute__((ext_vector_type(4))) float  f32x4;
typedef __attribute__((ext_vector_type(4))) unsigned int u32x4;

static __device__ __forceinline__ unsigned short f2bf(float f) {
    unsigned int u = __float_as_uint(f);
    unsigned int r = (u + 0x7fffu + ((u >> 16) & 1u)) >> 16;   // RNE
    return (unsigned short)r;
}

// ---------------- fc_w [64][VOCAB] f32  ->  wt [VPAD][64] bf16 (transposed, zero-padded)
__global__ __launch_bounds__(256) void prep_wt(const float* __restrict__ fcw,
                                               unsigned short* __restrict__ wt) {
    int n = blockIdx.x * 256 + threadIdx.x;
    if (n >= VPAD) return;
    unsigned int packed[32];
    if (n < VOCAB) {
        #pragma unroll
        for (int k2 = 0; k2 < 32; ++k2) {
            unsigned int lo = f2bf(fcw[(size_t)(2*k2)   * VOCAB + n]);
            unsigned int hi = f2bf(fcw[(size_t)(2*k2+1) * VOCAB + n]);
            packed[k2] = lo | (hi << 16);
        }
    } else {
        #pragma unroll
        for (int k2 = 0; k2 < 32; ++k2) packed[k2] = 0u;
    }
    u32x4* dst = (u32x4*)(wt + (size_t)n * 64);
    #pragma unroll
    for (int i = 0; i < 8; ++i) {
        u32x4 v = { packed[4*i], packed[4*i+1], packed[4*i+2], packed[4*i+3] };
        dst[i] = v;
    }
}

// ---------------- embed gather + pos add -> h ; LN1 -> hn   (one wave per row)
__global__ __launch_bounds__(256) void embed_ln(const int* __restrict__ x,
                                                const float* __restrict__ ew,
                                                const float* __restrict__ pw,
                                                const float* __restrict__ g,
                                                const float* __restrict__ bb,
                                                float* __restrict__ h,
                                                float* __restrict__ hn) {
    int row = blockIdx.x * 4 + (threadIdx.x >> 6);
    int e   = threadIdx.x & 63;
    int tok = x[row];
    float v = ew[(size_t)tok * 64 + e] + pw[(size_t)(row & 255) * 64 + e];
    h[(size_t)row * 64 + e] = v;
    float s = v;
    #pragma unroll
    for (int m = 32; m >= 1; m >>= 1) s += __shfl_xor(s, m, 64);
    float mu = s * (1.f/64.f);
    float d  = v - mu;
    float s2 = d * d;
    #pragma unroll
    for (int m = 32; m >= 1; m >>= 1) s2 += __shfl_xor(s2, m, 64);
    float var = s2 * (1.f/64.f);
    hn[(size_t)row * 64 + e] = d * rsqrtf(var + LNEPS) * g[e] + bb[e];
}

// ---------------- Q,K,V GEMMs.  wave0->Q, wave1->K (stored transposed), wave2->V
__global__ __launch_bounds__(192) void qkv(const float* __restrict__ hn,
                                           const float* __restrict__ wq,
                                           const float* __restrict__ wk,
                                           const float* __restrict__ wv,
                                           float* __restrict__ q,
                                           float* __restrict__ kt,
                                           float* __restrict__ v) {
    int wave = threadIdx.x >> 6;     // 0..2
    int j    = threadIdx.x & 63;
    const float* W = (wave == 0) ? wq : ((wave == 1) ? wk : wv);
    int m0 = blockIdx.x * 16;
    for (int r = 0; r < 16; ++r) {
        int m = m0 + r;
        const float* hr = hn + (size_t)m * 64;   // uniform -> scalar loads
        float acc = 0.f;
        #pragma unroll
        for (int e = 0; e < 64; ++e) acc += hr[e] * W[e * 64 + j];
        if (wave == 0)      q[(size_t)m * 64 + j] = acc;
        else if (wave == 1) {
            int b = m >> 8, t = m & 255;
            kt[((size_t)b * 64 + j) * 256 + t] = acc;
        } else              v[(size_t)m * 64 + j] = acc;
    }
}

// ---------------- scores (QK^T/8, causal) + softmax -> P f32.  4 query rows per block.
__global__ __launch_bounds__(256) void attn_sm(const float* __restrict__ q,
                                               const float* __restrict__ kt,
                                               float* __restrict__ p) {
    int b   = blockIdx.y;            // 0..31
    int m4  = blockIdx.x;            // 0..63
    int key = threadIdx.x;           // 0..255
    int wave = key >> 6, lane = key & 63;
    const float* ktb = kt + (size_t)b * 64 * 256;
    const float* qb  = q  + ((size_t)b * 256 + m4 * 4) * 64;   // 4 rows, uniform
    float s0=0.f, s1=0.f, s2=0.f, s3=0.f;
    for (int e = 0; e < 64; ++e) {
        float kv = ktb[e * 256 + key];
        s0 += qb[e]       * kv;
        s1 += qb[64 + e]  * kv;
        s2 += qb[128 + e] * kv;
        s3 += qb[192 + e] * kv;
    }
    float sv[4] = { s0*0.125f, s1*0.125f, s2*0.125f, s3*0.125f };
    __shared__ float redm[4][4], reds[4][4];
    float pe[4];
    #pragma unroll
    for (int r = 0; r < 4; ++r) {
        int mrow = m4 * 4 + r;
        float xv = (key <= mrow) ? sv[r] : -1e30f;
        sv[r] = xv;
        float wm = xv;
        #pragma unroll
        for (int mm = 32; mm >= 1; mm >>= 1) wm = fmaxf(wm, __shfl_xor(wm, mm, 64));
        if (lane == 0) redm[wave][r] = wm;
    }
    __syncthreads();
    #pragma unroll
    for (int r = 0; r < 4; ++r) {
        float M = fmaxf(fmaxf(redm[0][r], redm[1][r]), fmaxf(redm[2][r], redm[3][r]));
        float e_ = expf(sv[r] - M);
        pe[r] = e_;
        float ws = e_;
        #pragma unroll
        for (int mm = 32; mm >= 1; mm >>= 1) ws += __shfl_xor(ws, mm, 64);
        if (lane == 0) reds[wave][r] = ws;
    }
    __syncthreads();
    float* pb = p + ((size_t)b * 256 + m4 * 4) * 256;
    #pragma unroll
    for (int r = 0; r < 4; ++r) {
        float S = reds[0][r] + reds[1][r] + reds[2][r] + reds[3][r];
        pb[r * 256 + key] = pe[r] / S;
    }
}

// ---------------- ctx = P@V ; h2 = h + ctx ; LNf -> hf bf16.  One wave per row.
__global__ __launch_bounds__(256) void ctx_lnf(const float* __restrict__ p,
                                               const float* __restrict__ v,
                                               const float* __restrict__ h,
                                               const float* __restrict__ g,
                                               const float* __restrict__ bb,
                                               unsigned short* __restrict__ hf) {
    int m = blockIdx.x * 4 + (threadIdx.x >> 6);
    int n = threadIdx.x & 63;
    int b = m >> 8, t = m & 255;
    const float* pr = p + ((size_t)b * 256 + t) * 256;   // uniform -> scalar loads
    const float* vb = v + (size_t)b * 256 * 64;
    float acc = 0.f;
    for (int key = 0; key <= t; ++key)
        acc += pr[key] * vb[key * 64 + n];
    float h2 = h[(size_t)m * 64 + n] + acc;
    float s = h2;
    #pragma unroll
    for (int mm = 32; mm >= 1; mm >>= 1) s += __shfl_xor(s, mm, 64);
    float mu = s * (1.f/64.f);
    float d  = h2 - mu;
    float s2 = d * d;
    #pragma unroll
    for (int mm = 32; mm >= 1; mm >>= 1) s2 += __shfl_xor(s2, mm, 64);
    float var = s2 * (1.f/64.f);
    hf[(size_t)m * 64 + n] = f2bf(d * rsqrtf(var + LNEPS) * g[n] + bb[n]);
}

// ---------------- logits = hf @ fc_w + fc_b  (bf16 MFMA, f32 out)
// No LDS, no barriers. Swapped MFMA (A=wt, B=hf): lane's c[0..3] = 4
// consecutive vocab cols -> direct f32x4 store from the accumulator (R6
// proved temporally-adjacent 64B chunks merge to full lines: WRITE was exact).
// 2-deep register pipeline: LOAD(s+1,g) (wt+bias) issues between store
// groups, so each MFMA's vmcnt wait only needs >=1-group-old loads -- newer
// stores stay in flight (vmcnt is one FIFO shared by loads+stores: the R6
// killer). Grid 2048 = 512 bands x 4 vocab-quarters, XCD-slab mapped; 16
// desynchronized waves/CU keep store issue continuous.
__global__ __launch_bounds__(256, 4) void final_gemm(const unsigned short* __restrict__ hf,
                                                     const unsigned short* __restrict__ wt,
                                                     const float* __restrict__ bias,
                                                     float* __restrict__ out) {
    int bid = blockIdx.x;                 // 0..2047
    int xcd = bid & 7;
    int r   = bid >> 3;                   // 0..255
    int quarter = r >> 6;                 // 0..3
    int mb  = xcd * 64 + (r & 63);        // band 0..511
    int m0  = mb * 16;
    int qs  = quarter * 25;
    int qn  = (quarter == 3) ? 24 : 25;   // 25+25+25+24 = 99 stripes

    int wave = threadIdx.x >> 6, lane = threadIdx.x & 63;
    int l15 = lane & 15, lk = lane >> 4;

    // B-operand: this band's 16 token rows (loaded once)
    const bf16x8* hrow = (const bf16x8*)(hf + (size_t)(m0 + l15) * 64);
    bf16x8 hb0 = hrow[lk];       // k 0..31
    bf16x8 hb1 = hrow[4 + lk];   // k 32..63

    float* orow = out + (size_t)(m0 + l15) * VOCAB;

    // double-buffered fragments: 2 groups of 4 tiles (wave covers 128 vocab)
    bf16x8 w0a[4], w1a[4], w0b[4], w1b[4];
    f32x4  bva[4], bvb[4];

    auto LOADG = [&](int s, int g, bf16x8 (&w0)[4], bf16x8 (&w1)[4], f32x4 (&bv)[4]) {
        int vb = s * SCOLS + wave * 128 + g * 64;
        #pragma unroll
        for (int t = 0; t < 4; ++t) {
            const bf16x8* wrow = (const bf16x8*)(wt + (size_t)(vb + t * 16 + l15) * 64);
            w0[t] = wrow[lk];
            w1[t] = wrow[4 + lk];
            int bc = vb + t * 16 + lk * 4;
            if (bc + 4 <= VOCAB) {
                bv[t] = *(const f32x4*)(bias + bc);
            } else {
                #pragma unroll
                for (int e = 0; e < 4; ++e) bv[t][e] = (bc + e < VOCAB) ? bias[bc + e] : 0.f;
            }
        }
    };

    auto CSTORE = [&](int s, int g, bf16x8 (&w0)[4], bf16x8 (&w1)[4], f32x4 (&bv)[4]) {
        int vb = s * SCOLS + wave * 128 + g * 64;
        #pragma unroll
        for (int t = 0; t < 4; ++t) {
            f32x4 c = {0.f, 0.f, 0.f, 0.f};
            c = __builtin_amdgcn_mfma_f32_16x16x32_bf16(w0[t], hb0, c, 0, 0, 0);
            c = __builtin_amdgcn_mfma_f32_16x16x32_bf16(w1[t], hb1, c, 0, 0, 0);
            c += bv[t];
            int vc = vb + t * 16 + lk * 4;
            if (vc + 4 <= VOCAB) {
                *(f32x4*)(orow + vc) = c;
            } else {
                #pragma unroll
                for (int e = 0; e < 4; ++e)
                    if (vc + e < VOCAB) orow[vc + e] = c[e];
            }
        }
    };

    LOADG(qs, 0, w0a, w1a, bva);
    LOADG(qs, 1, w0b, w1b, bvb);
    for (int s = qs; s < qs + qn; ++s) {
        CSTORE(s, 0, w0a, w1a, bva);
        if (s + 1 < qs + qn) LOADG(s + 1, 0, w0a, w1a, bva);
        CSTORE(s, 1, w0b, w1b, bvb);
        if (s + 1 < qs + qn) LOADG(s + 1, 1, w0b, w1b, bvb);
    }
}

extern "C" void kernel_launch(void* const* d_in, const int* in_sizes, int n_in,
                              void* d_out, int out_size, void* d_ws, size_t ws_size,
                              hipStream_t stream) {
    const int*   x    = (const int*)  d_in[0];
    const float* ew   = (const float*)d_in[1];
    const float* pw   = (const float*)d_in[2];
    const float* ln1g = (const float*)d_in[3];
    const float* ln1b = (const float*)d_in[4];
    const float* wq   = (const float*)d_in[5];
    const float* wk   = (const float*)d_in[6];
    const float* wv   = (const float*)d_in[7];
    const float* lnfg = (const float*)d_in[8];
    const float* lnfb = (const float*)d_in[9];
    const float* fcw  = (const float*)d_in[10];
    const float* fcb  = (const float*)d_in[11];
    float* out = (float*)d_out;

    char* ws = (char*)d_ws;
    float*          h  = (float*)(ws + 0);                    //  0..2 MB
    float*          hn = (float*)(ws + (2u<<20));             //  2..4 MB (dead after qkv)
    unsigned short* hf = (unsigned short*)(ws + (2u<<20));    //  reuses hn slot (1 MB)
    float*          q  = (float*)(ws + (4u<<20));             //  4..6 MB
    float*          kt = (float*)(ws + (6u<<20));             //  6..8 MB
    float*          v  = (float*)(ws + (8u<<20));             //  8..10 MB
    float*          p  = (float*)(ws + (10u<<20));            // 10..18 MB
    unsigned short* wt = (unsigned short*)(ws + (18u<<20));   // 18..24.2 MB

    prep_wt  <<<dim3(VPAD / 256),  dim3(256), 0, stream>>>(fcw, wt);
    embed_ln <<<dim3(NROWS / 4),   dim3(256), 0, stream>>>(x, ew, pw, ln1g, ln1b, h, hn);
    qkv      <<<dim3(NROWS / 16),  dim3(192), 0, stream>>>(hn, wq, wk, wv, q, kt, v);
    attn_sm  <<<dim3(64, 32),      dim3(256), 0, stream>>>(q, kt, p);
    ctx_lnf  <<<dim3(NROWS / 4),   dim3(256), 0, stream>>>(p, v, h, lnfg, lnfb, hf);
    final_gemm<<<dim3(2048),       dim3(256), 0, stream>>>(hf, wt, fcb, out);
}

// Round 8
// 826.497 us; speedup vs baseline: 1.3501x; 1.2271x over previous
//
#include <hip/hip_runtime.h>
#include <hip/hip_bf16.h>

#define EMBED  64
#define TLEN   256
#define BATCH  32
#define NROWS  (BATCH*TLEN)      // 8192
#define VOCAB  50257
#define BCOLS  512
#define NB     99                // col stripes
#define VPAD   (NB*BCOLS)        // 50688, zero-padded B rows
#define LNEPS  1e-5f

typedef __attribute__((ext_vector_type(8))) short  bf16x8;
typedef __attribute__((ext_vector_type(4))) float  f32x4;
typedef __attribute__((ext_vector_type(4))) unsigned int u32x4;

static __device__ __forceinline__ unsigned short f2bf(float f) {
    unsigned int u = __float_as_uint(f);
    unsigned int r = (u + 0x7fffu + ((u >> 16) & 1u)) >> 16;   // RNE
    return (unsigned short)r;
}

// ---------------- fc_w [64][VOCAB] f32  ->  wt [VPAD][64] bf16 (transposed, zero-padded)
__global__ __launch_bounds__(256) void prep_wt(const float* __restrict__ fcw,
                                               unsigned short* __restrict__ wt) {
    int n = blockIdx.x * 256 + threadIdx.x;
    if (n >= VPAD) return;
    unsigned int packed[32];
    if (n < VOCAB) {
        #pragma unroll
        for (int k2 = 0; k2 < 32; ++k2) {
            unsigned int lo = f2bf(fcw[(size_t)(2*k2)   * VOCAB + n]);
            unsigned int hi = f2bf(fcw[(size_t)(2*k2+1) * VOCAB + n]);
            packed[k2] = lo | (hi << 16);
        }
    } else {
        #pragma unroll
        for (int k2 = 0; k2 < 32; ++k2) packed[k2] = 0u;
    }
    u32x4* dst = (u32x4*)(wt + (size_t)n * 64);
    #pragma unroll
    for (int i = 0; i < 8; ++i) {
        u32x4 v = { packed[4*i], packed[4*i+1], packed[4*i+2], packed[4*i+3] };
        dst[i] = v;
    }
}

// ---------------- embed gather + pos add -> h ; LN1 -> hn   (one wave per row)
__global__ __launch_bounds__(256) void embed_ln(const int* __restrict__ x,
                                                const float* __restrict__ ew,
                                                const float* __restrict__ pw,
                                                const float* __restrict__ g,
                                                const float* __restrict__ bb,
                                                float* __restrict__ h,
                                                float* __restrict__ hn) {
    int row = blockIdx.x * 4 + (threadIdx.x >> 6);
    int e   = threadIdx.x & 63;
    int tok = x[row];
    float v = ew[(size_t)tok * 64 + e] + pw[(size_t)(row & 255) * 64 + e];
    h[(size_t)row * 64 + e] = v;
    float s = v;
    #pragma unroll
    for (int m = 32; m >= 1; m >>= 1) s += __shfl_xor(s, m, 64);
    float mu = s * (1.f/64.f);
    float d  = v - mu;
    float s2 = d * d;
    #pragma unroll
    for (int m = 32; m >= 1; m >>= 1) s2 += __shfl_xor(s2, m, 64);
    float var = s2 * (1.f/64.f);
    hn[(size_t)row * 64 + e] = d * rsqrtf(var + LNEPS) * g[e] + bb[e];
}

// ---------------- Q,K,V GEMMs.  wave0->Q, wave1->K (stored transposed), wave2->V
__global__ __launch_bounds__(192) void qkv(const float* __restrict__ hn,
                                           const float* __restrict__ wq,
                                           const float* __restrict__ wk,
                                           const float* __restrict__ wv,
                                           float* __restrict__ q,
                                           float* __restrict__ kt,
                                           float* __restrict__ v) {
    int wave = threadIdx.x >> 6;     // 0..2
    int j    = threadIdx.x & 63;
    const float* W = (wave == 0) ? wq : ((wave == 1) ? wk : wv);
    int m0 = blockIdx.x * 16;
    for (int r = 0; r < 16; ++r) {
        int m = m0 + r;
        const float* hr = hn + (size_t)m * 64;   // uniform -> scalar loads
        float acc = 0.f;
        #pragma unroll
        for (int e = 0; e < 64; ++e) acc += hr[e] * W[e * 64 + j];
        if (wave == 0)      q[(size_t)m * 64 + j] = acc;
        else if (wave == 1) {
            int b = m >> 8, t = m & 255;
            kt[((size_t)b * 64 + j) * 256 + t] = acc;
        } else              v[(size_t)m * 64 + j] = acc;
    }
}

// ---------------- scores (QK^T/8, causal) + softmax -> P f32.  4 query rows per block.
__global__ __launch_bounds__(256) void attn_sm(const float* __restrict__ q,
                                               const float* __restrict__ kt,
                                               float* __restrict__ p) {
    int b   = blockIdx.y;            // 0..31
    int m4  = blockIdx.x;            // 0..63
    int key = threadIdx.x;           // 0..255
    int wave = key >> 6, lane = key & 63;
    const float* ktb = kt + (size_t)b * 64 * 256;
    const float* qb  = q  + ((size_t)b * 256 + m4 * 4) * 64;   // 4 rows, uniform
    float s0=0.f, s1=0.f, s2=0.f, s3=0.f;
    for (int e = 0; e < 64; ++e) {
        float kv = ktb[e * 256 + key];
        s0 += qb[e]       * kv;
        s1 += qb[64 + e]  * kv;
        s2 += qb[128 + e] * kv;
        s3 += qb[192 + e] * kv;
    }
    float sv[4] = { s0*0.125f, s1*0.125f, s2*0.125f, s3*0.125f };
    __shared__ float redm[4][4], reds[4][4];
    float pe[4];
    #pragma unroll
    for (int r = 0; r < 4; ++r) {
        int mrow = m4 * 4 + r;
        float xv = (key <= mrow) ? sv[r] : -1e30f;
        sv[r] = xv;
        float wm = xv;
        #pragma unroll
        for (int mm = 32; mm >= 1; mm >>= 1) wm = fmaxf(wm, __shfl_xor(wm, mm, 64));
        if (lane == 0) redm[wave][r] = wm;
    }
    __syncthreads();
    #pragma unroll
    for (int r = 0; r < 4; ++r) {
        float M = fmaxf(fmaxf(redm[0][r], redm[1][r]), fmaxf(redm[2][r], redm[3][r]));
        float e_ = expf(sv[r] - M);
        pe[r] = e_;
        float ws = e_;
        #pragma unroll
        for (int mm = 32; mm >= 1; mm >>= 1) ws += __shfl_xor(ws, mm, 64);
        if (lane == 0) reds[wave][r] = ws;
    }
    __syncthreads();
    float* pb = p + ((size_t)b * 256 + m4 * 4) * 256;
    #pragma unroll
    for (int r = 0; r < 4; ++r) {
        float S = reds[0][r] + reds[1][r] + reds[2][r] + reds[3][r];
        pb[r * 256 + key] = pe[r] / S;
    }
}

// ---------------- ctx = P@V ; h2 = h + ctx ; LNf -> hf bf16.  One wave per row.
__global__ __launch_bounds__(256) void ctx_lnf(const float* __restrict__ p,
                                               const float* __restrict__ v,
                                               const float* __restrict__ h,
                                               const float* __restrict__ g,
                                               const float* __restrict__ bb,
                                               unsigned short* __restrict__ hf) {
    int m = blockIdx.x * 4 + (threadIdx.x >> 6);
    int n = threadIdx.x & 63;
    int b = m >> 8, t = m & 255;
    const float* pr = p + ((size_t)b * 256 + t) * 256;   // uniform -> scalar loads
    const float* vb = v + (size_t)b * 256 * 64;
    float acc = 0.f;
    for (int key = 0; key <= t; ++key)
        acc += pr[key] * vb[key * 64 + n];
    float h2 = h[(size_t)m * 64 + n] + acc;
    float s = h2;
    #pragma unroll
    for (int mm = 32; mm >= 1; mm >>= 1) s += __shfl_xor(s, mm, 64);
    float mu = s * (1.f/64.f);
    float d  = h2 - mu;
    float s2 = d * d;
    #pragma unroll
    for (int mm = 32; mm >= 1; mm >>= 1) s2 += __shfl_xor(s2, mm, 64);
    float var = s2 * (1.f/64.f);
    hf[(size_t)m * 64 + n] = f2bf(d * rsqrtf(var + LNEPS) * g[n] + bb[n]);
}

// ---------------- logits = hf @ fc_w + fc_b  (bf16 MFMA, f32 out)
// R3 block internals (16 rows x 512 cols, LDS-staged epilogue: each row's 2KB
// written as back-to-back 256B dwordx4 runs; one barrier; stores never waited
// on inside the block). Grid mapping is the R1-style COLUMN-FAST order:
// blockIdx.x = nb (stripe), blockIdx.y = mb (band). The ~1024 resident blocks
// then cover ~10 adjacent 16-row bands x the full vocab -> a compact ~30MB
// write front that sweeps the output in address order (the empirical law
// across R1/R2/R3/R6/R7: DRAM write rate tracks compactness of the
// concurrent write window; widest window = 1.7 TB/s, R1's compact front =
// 4.2 TB/s). wt (6.2MB) is re-read per band but stays L3-resident.
__global__ __launch_bounds__(256) void final_gemm(const unsigned short* __restrict__ hf,
                                                  const unsigned short* __restrict__ wt,
                                                  const float* __restrict__ bias,
                                                  float* __restrict__ out) {
    int nb = blockIdx.x;             // 0..98   (FAST axis -> column-major front)
    int mb = blockIdx.y;             // 0..511
    int tid  = threadIdx.x;
    int wave = tid >> 6, lane = tid & 63;
    int l15 = lane & 15, lk = lane >> 4;
    int m0 = mb * 16;

    __shared__ float lds[16 * 520];        // [row][520] (pad 8 floats)

    const bf16x8* arow = (const bf16x8*)(hf + (size_t)(m0 + l15) * 64);
    bf16x8 a0 = arow[lk];        // k 0..31
    bf16x8 a1 = arow[4 + lk];    // k 32..63

    #pragma unroll
    for (int nt = 0; nt < 8; ++nt) {
        int lcol = wave * 128 + nt * 16 + l15;         // 0..511
        int col  = nb * BCOLS + lcol;
        const bf16x8* brow = (const bf16x8*)(wt + (size_t)col * 64);
        f32x4 c = {0.f, 0.f, 0.f, 0.f};
        c = __builtin_amdgcn_mfma_f32_16x16x32_bf16(a0, brow[lk],     c, 0, 0, 0);
        c = __builtin_amdgcn_mfma_f32_16x16x32_bf16(a1, brow[4 + lk], c, 0, 0, 0);
        float bv = (col < VOCAB) ? bias[col] : 0.f;
        #pragma unroll
        for (int r = 0; r < 4; ++r)
            lds[(lk * 4 + r) * 520 + lcol] = c[r] + bv;
    }
    __syncthreads();

    // store phase: thread t -> row t>>4; run i: 16 lanes cover 256B contiguous
    int row = tid >> 4, cc = tid & 15;
    float* orow = out + (size_t)(m0 + row) * VOCAB + nb * BCOLS;
    const float* lrow = lds + row * 520;
    #pragma unroll
    for (int i = 0; i < 8; ++i) {
        int lcol = i * 64 + cc * 4;
        f32x4 vv = *(const f32x4*)(lrow + lcol);
        int cs = nb * BCOLS + lcol;
        if (cs + 4 <= VOCAB) {
            *(f32x4*)(orow + lcol) = vv;
        } else {
            #pragma unroll
            for (int e = 0; e < 4; ++e)
                if (cs + e < VOCAB) orow[lcol + e] = vv[e];
        }
    }
}

extern "C" void kernel_launch(void* const* d_in, const int* in_sizes, int n_in,
                              void* d_out, int out_size, void* d_ws, size_t ws_size,
                              hipStream_t stream) {
    const int*   x    = (const int*)  d_in[0];
    const float* ew   = (const float*)d_in[1];
    const float* pw   = (const float*)d_in[2];
    const float* ln1g = (const float*)d_in[3];
    const float* ln1b = (const float*)d_in[4];
    const float* wq   = (const float*)d_in[5];
    const float* wk   = (const float*)d_in[6];
    const float* wv   = (const float*)d_in[7];
    const float* lnfg = (const float*)d_in[8];
    const float* lnfb = (const float*)d_in[9];
    const float* fcw  = (const float*)d_in[10];
    const float* fcb  = (const float*)d_in[11];
    float* out = (float*)d_out;

    char* ws = (char*)d_ws;
    float*          h  = (float*)(ws + 0);                    //  0..2 MB
    float*          hn = (float*)(ws + (2u<<20));             //  2..4 MB (dead after qkv)
    unsigned short* hf = (unsigned short*)(ws + (2u<<20));    //  reuses hn slot (1 MB)
    float*          q  = (float*)(ws + (4u<<20));             //  4..6 MB
    float*          kt = (float*)(ws + (6u<<20));             //  6..8 MB
    float*          v  = (float*)(ws + (8u<<20));             //  8..10 MB
    float*          p  = (float*)(ws + (10u<<20));            // 10..18 MB
    unsigned short* wt = (unsigned short*)(ws + (18u<<20));   // 18..24.2 MB

    prep_wt  <<<dim3(VPAD / 256),  dim3(256), 0, stream>>>(fcw, wt);
    embed_ln <<<dim3(NROWS / 4),   dim3(256), 0, stream>>>(x, ew, pw, ln1g, ln1b, h, hn);
    qkv      <<<dim3(NROWS / 16),  dim3(192), 0, stream>>>(hn, wq, wk, wv, q, kt, v);
    attn_sm  <<<dim3(64, 32),      dim3(256), 0, stream>>>(q, kt, p);
    ctx_lnf  <<<dim3(NROWS / 4),   dim3(256), 0, stream>>>(p, v, h, lnfg, lnfb, hf);
    final_gemm<<<dim3(NB, 512),    dim3(256), 0, stream>>>(hf, wt, fcb, out);
}

// Round 9
// 706.611 us; speedup vs baseline: 1.5791x; 1.1697x over previous
//
#include <hip/hip_runtime.h>
#include <hip/hip_bf16.h>

#define EMBED  64
#define TLEN   256
#define BATCH  32
#define NROWS  (BATCH*TLEN)      // 8192
#define VOCAB  50257
#define BCOLS  512
#define NB     99                // real col stripes (50688 padded cols in wt)
#define NSF    13                // stripes per XCD slab (13*8 = 104 >= 99)
#define VPAD   (NB*BCOLS)        // 50688, zero-padded B rows
#define LNEPS  1e-5f

typedef __attribute__((ext_vector_type(8))) short  bf16x8;
typedef __attribute__((ext_vector_type(4))) float  f32x4;
typedef __attribute__((ext_vector_type(4))) unsigned int u32x4;

static __device__ __forceinline__ unsigned short f2bf(float f) {
    unsigned int u = __float_as_uint(f);
    unsigned int r = (u + 0x7fffu + ((u >> 16) & 1u)) >> 16;   // RNE
    return (unsigned short)r;
}

// ---------------- fc_w [64][VOCAB] f32  ->  wt [VPAD][64] bf16 (transposed, zero-padded)
__global__ __launch_bounds__(256) void prep_wt(const float* __restrict__ fcw,
                                               unsigned short* __restrict__ wt) {
    int n = blockIdx.x * 256 + threadIdx.x;
    if (n >= VPAD) return;
    unsigned int packed[32];
    if (n < VOCAB) {
        #pragma unroll
        for (int k2 = 0; k2 < 32; ++k2) {
            unsigned int lo = f2bf(fcw[(size_t)(2*k2)   * VOCAB + n]);
            unsigned int hi = f2bf(fcw[(size_t)(2*k2+1) * VOCAB + n]);
            packed[k2] = lo | (hi << 16);
        }
    } else {
        #pragma unroll
        for (int k2 = 0; k2 < 32; ++k2) packed[k2] = 0u;
    }
    u32x4* dst = (u32x4*)(wt + (size_t)n * 64);
    #pragma unroll
    for (int i = 0; i < 8; ++i) {
        u32x4 v = { packed[4*i], packed[4*i+1], packed[4*i+2], packed[4*i+3] };
        dst[i] = v;
    }
}

// ---------------- embed gather + pos add -> h ; LN1 -> hn   (one wave per row)
__global__ __launch_bounds__(256) void embed_ln(const int* __restrict__ x,
                                                const float* __restrict__ ew,
                                                const float* __restrict__ pw,
                                                const float* __restrict__ g,
                                                const float* __restrict__ bb,
                                                float* __restrict__ h,
                                                float* __restrict__ hn) {
    int row = blockIdx.x * 4 + (threadIdx.x >> 6);
    int e   = threadIdx.x & 63;
    int tok = x[row];
    float v = ew[(size_t)tok * 64 + e] + pw[(size_t)(row & 255) * 64 + e];
    h[(size_t)row * 64 + e] = v;
    float s = v;
    #pragma unroll
    for (int m = 32; m >= 1; m >>= 1) s += __shfl_xor(s, m, 64);
    float mu = s * (1.f/64.f);
    float d  = v - mu;
    float s2 = d * d;
    #pragma unroll
    for (int m = 32; m >= 1; m >>= 1) s2 += __shfl_xor(s2, m, 64);
    float var = s2 * (1.f/64.f);
    hn[(size_t)row * 64 + e] = d * rsqrtf(var + LNEPS) * g[e] + bb[e];
}

// ---------------- Q,K,V GEMMs.  wave0->Q, wave1->K (stored transposed), wave2->V
__global__ __launch_bounds__(192) void qkv(const float* __restrict__ hn,
                                           const float* __restrict__ wq,
                                           const float* __restrict__ wk,
                                           const float* __restrict__ wv,
                                           float* __restrict__ q,
                                           float* __restrict__ kt,
                                           float* __restrict__ v) {
    int wave = threadIdx.x >> 6;     // 0..2
    int j    = threadIdx.x & 63;
    const float* W = (wave == 0) ? wq : ((wave == 1) ? wk : wv);
    int m0 = blockIdx.x * 16;
    for (int r = 0; r < 16; ++r) {
        int m = m0 + r;
        const float* hr = hn + (size_t)m * 64;   // uniform -> scalar loads
        float acc = 0.f;
        #pragma unroll
        for (int e = 0; e < 64; ++e) acc += hr[e] * W[e * 64 + j];
        if (wave == 0)      q[(size_t)m * 64 + j] = acc;
        else if (wave == 1) {
            int b = m >> 8, t = m & 255;
            kt[((size_t)b * 64 + j) * 256 + t] = acc;
        } else              v[(size_t)m * 64 + j] = acc;
    }
}

// ---------------- scores (QK^T/8, causal) + softmax -> P f32.  4 query rows per block.
__global__ __launch_bounds__(256) void attn_sm(const float* __restrict__ q,
                                               const float* __restrict__ kt,
                                               float* __restrict__ p) {
    int b   = blockIdx.y;            // 0..31
    int m4  = blockIdx.x;            // 0..63
    int key = threadIdx.x;           // 0..255
    int wave = key >> 6, lane = key & 63;
    const float* ktb = kt + (size_t)b * 64 * 256;
    const float* qb  = q  + ((size_t)b * 256 + m4 * 4) * 64;   // 4 rows, uniform
    float s0=0.f, s1=0.f, s2=0.f, s3=0.f;
    for (int e = 0; e < 64; ++e) {
        float kv = ktb[e * 256 + key];
        s0 += qb[e]       * kv;
        s1 += qb[64 + e]  * kv;
        s2 += qb[128 + e] * kv;
        s3 += qb[192 + e] * kv;
    }
    float sv[4] = { s0*0.125f, s1*0.125f, s2*0.125f, s3*0.125f };
    __shared__ float redm[4][4], reds[4][4];
    float pe[4];
    #pragma unroll
    for (int r = 0; r < 4; ++r) {
        int mrow = m4 * 4 + r;
        float xv = (key <= mrow) ? sv[r] : -1e30f;
        sv[r] = xv;
        float wm = xv;
        #pragma unroll
        for (int mm = 32; mm >= 1; mm >>= 1) wm = fmaxf(wm, __shfl_xor(wm, mm, 64));
        if (lane == 0) redm[wave][r] = wm;
    }
    __syncthreads();
    #pragma unroll
    for (int r = 0; r < 4; ++r) {
        float M = fmaxf(fmaxf(redm[0][r], redm[1][r]), fmaxf(redm[2][r], redm[3][r]));
        float e_ = expf(sv[r] - M);
        pe[r] = e_;
        float ws = e_;
        #pragma unroll
        for (int mm = 32; mm >= 1; mm >>= 1) ws += __shfl_xor(ws, mm, 64);
        if (lane == 0) reds[wave][r] = ws;
    }
    __syncthreads();
    float* pb = p + ((size_t)b * 256 + m4 * 4) * 256;
    #pragma unroll
    for (int r = 0; r < 4; ++r) {
        float S = reds[0][r] + reds[1][r] + reds[2][r] + reds[3][r];
        pb[r * 256 + key] = pe[r] / S;
    }
}

// ---------------- ctx = P@V ; h2 = h + ctx ; LNf -> hf bf16.  One wave per row.
__global__ __launch_bounds__(256) void ctx_lnf(const float* __restrict__ p,
                                               const float* __restrict__ v,
                                               const float* __restrict__ h,
                                               const float* __restrict__ g,
                                               const float* __restrict__ bb,
                                               unsigned short* __restrict__ hf) {
    int m = blockIdx.x * 4 + (threadIdx.x >> 6);
    int n = threadIdx.x & 63;
    int b = m >> 8, t = m & 255;
    const float* pr = p + ((size_t)b * 256 + t) * 256;   // uniform -> scalar loads
    const float* vb = v + (size_t)b * 256 * 64;
    float acc = 0.f;
    for (int key = 0; key <= t; ++key)
        acc += pr[key] * vb[key * 64 + n];
    float h2 = h[(size_t)m * 64 + n] + acc;
    float s = h2;
    #pragma unroll
    for (int mm = 32; mm >= 1; mm >>= 1) s += __shfl_xor(s, mm, 64);
    float mu = s * (1.f/64.f);
    float d  = h2 - mu;
    float s2 = d * d;
    #pragma unroll
    for (int mm = 32; mm >= 1; mm >>= 1) s2 += __shfl_xor(s2, mm, 64);
    float var = s2 * (1.f/64.f);
    hf[(size_t)m * 64 + n] = f2bf(d * rsqrtf(var + LNEPS) * g[n] + bb[n]);
}

// ---------------- logits = hf @ fc_w + fc_b  (bf16 MFMA, f32 out)
// Block internals identical to R3/R8 (16 rows x 512 cols, LDS-staged epilogue,
// 256B dwordx4 runs, one barrier, stores never waited on). New grid mapping
// satisfies BOTH empirical requirements discovered in R3 vs R8:
//  (a) wt read locality: stripe nb = sf*8 + xcd -> each XCD permanently owns
//      13 stripes = 832KB of wt, L2-resident for the whole kernel (wt fetched
//      from L3/HBM ~once per XCD = ~50MB, vs R8's 3.2GB L2-thrash).
//  (b) write-front contiguity: within each XCD, sf cycles FAST and the band
//      mb = j/13 advances SLOW -> all 8 XCDs sweep the same ~10-band window
//      concurrently -> the global write front is ~160 consecutive rows x full
//      vocab, one contiguous ~32MB region moving in address order (the fill
//      kernel's 6.5 TB/s pattern).
// Dead padding stripes (nb >= 99; 5 of 104, on 5 different XCDs) exit early.
__global__ __launch_bounds__(256) void final_gemm(const unsigned short* __restrict__ hf,
                                                  const unsigned short* __restrict__ wt,
                                                  const float* __restrict__ bias,
                                                  float* __restrict__ out) {
    int bid = blockIdx.x;            // 0..53247 (= 8 * 13 * 512)
    int xcd = bid & 7;
    int j   = bid >> 3;              // 0..6655
    int sf  = j % NSF;               // stripe-in-slab (FAST)
    int mb  = j / NSF;               // band 0..511 (SLOW, global sweep)
    int nb  = sf * 8 + xcd;          // global stripe 0..103
    if (nb >= NB) return;            // padding stripes

    int tid  = threadIdx.x;
    int wave = tid >> 6, lane = tid & 63;
    int l15 = lane & 15, lk = lane >> 4;
    int m0 = mb * 16;

    __shared__ float lds[16 * 520];        // [row][520] (pad 8 floats)

    const bf16x8* arow = (const bf16x8*)(hf + (size_t)(m0 + l15) * 64);
    bf16x8 a0 = arow[lk];        // k 0..31
    bf16x8 a1 = arow[4 + lk];    // k 32..63

    #pragma unroll
    for (int nt = 0; nt < 8; ++nt) {
        int lcol = wave * 128 + nt * 16 + l15;         // 0..511
        int col  = nb * BCOLS + lcol;
        const bf16x8* brow = (const bf16x8*)(wt + (size_t)col * 64);
        f32x4 c = {0.f, 0.f, 0.f, 0.f};
        c = __builtin_amdgcn_mfma_f32_16x16x32_bf16(a0, brow[lk],     c, 0, 0, 0);
        c = __builtin_amdgcn_mfma_f32_16x16x32_bf16(a1, brow[4 + lk], c, 0, 0, 0);
        float bv = (col < VOCAB) ? bias[col] : 0.f;
        #pragma unroll
        for (int r = 0; r < 4; ++r)
            lds[(lk * 4 + r) * 520 + lcol] = c[r] + bv;
    }
    __syncthreads();

    // store phase: thread t -> row t>>4; run i: 16 lanes cover 256B contiguous
    int row = tid >> 4, cc = tid & 15;
    float* orow = out + (size_t)(m0 + row) * VOCAB + nb * BCOLS;
    const float* lrow = lds + row * 520;
    #pragma unroll
    for (int i = 0; i < 8; ++i) {
        int lcol = i * 64 + cc * 4;
        f32x4 vv = *(const f32x4*)(lrow + lcol);
        int cs = nb * BCOLS + lcol;
        if (cs + 4 <= VOCAB) {
            *(f32x4*)(orow + lcol) = vv;
        } else {
            #pragma unroll
            for (int e = 0; e < 4; ++e)
                if (cs + e < VOCAB) orow[lcol + e] = vv[e];
        }
    }
}

extern "C" void kernel_launch(void* const* d_in, const int* in_sizes, int n_in,
                              void* d_out, int out_size, void* d_ws, size_t ws_size,
                              hipStream_t stream) {
    const int*   x    = (const int*)  d_in[0];
    const float* ew   = (const float*)d_in[1];
    const float* pw   = (const float*)d_in[2];
    const float* ln1g = (const float*)d_in[3];
    const float* ln1b = (const float*)d_in[4];
    const float* wq   = (const float*)d_in[5];
    const float* wk   = (const float*)d_in[6];
    const float* wv   = (const float*)d_in[7];
    const float* lnfg = (const float*)d_in[8];
    const float* lnfb = (const float*)d_in[9];
    const float* fcw  = (const float*)d_in[10];
    const float* fcb  = (const float*)d_in[11];
    float* out = (float*)d_out;

    char* ws = (char*)d_ws;
    float*          h  = (float*)(ws + 0);                    //  0..2 MB
    float*          hn = (float*)(ws + (2u<<20));             //  2..4 MB (dead after qkv)
    unsigned short* hf = (unsigned short*)(ws + (2u<<20));    //  reuses hn slot (1 MB)
    float*          q  = (float*)(ws + (4u<<20));             //  4..6 MB
    float*          kt = (float*)(ws + (6u<<20));             //  6..8 MB
    float*          v  = (float*)(ws + (8u<<20));             //  8..10 MB
    float*          p  = (float*)(ws + (10u<<20));            // 10..18 MB
    unsigned short* wt = (unsigned short*)(ws + (18u<<20));   // 18..24.2 MB

    prep_wt  <<<dim3(VPAD / 256),  dim3(256), 0, stream>>>(fcw, wt);
    embed_ln <<<dim3(NROWS / 4),   dim3(256), 0, stream>>>(x, ew, pw, ln1g, ln1b, h, hn);
    qkv      <<<dim3(NROWS / 16),  dim3(192), 0, stream>>>(hn, wq, wk, wv, q, kt, v);
    attn_sm  <<<dim3(64, 32),      dim3(256), 0, stream>>>(q, kt, p);
    ctx_lnf  <<<dim3(NROWS / 4),   dim3(256), 0, stream>>>(p, v, h, lnfg, lnfb, hf);
    final_gemm<<<dim3(8 * NSF * 512), dim3(256), 0, stream>>>(hf, wt, fcb, out);
}

// Round 10
// 695.397 us; speedup vs baseline: 1.6046x; 1.0161x over previous
//
#include <hip/hip_runtime.h>
#include <hip/hip_bf16.h>

#define EMBED  64
#define TLEN   256
#define BATCH  32
#define NROWS  (BATCH*TLEN)      // 8192
#define VOCAB  50257
#define BCOLS  256               // block tile cols
#define NB     198               // col stripes (198*256 = 50688)
#define VPAD   (NB*BCOLS)        // 50688, zero-padded B rows
#define LNEPS  1e-5f

typedef __attribute__((ext_vector_type(8))) short  bf16x8;
typedef __attribute__((ext_vector_type(4))) float  f32x4;
typedef __attribute__((ext_vector_type(4))) unsigned int u32x4;

static __device__ __forceinline__ unsigned short f2bf(float f) {
    unsigned int u = __float_as_uint(f);
    unsigned int r = (u + 0x7fffu + ((u >> 16) & 1u)) >> 16;   // RNE
    return (unsigned short)r;
}

// ---------------- fc_w [64][VOCAB] f32  ->  wt [VPAD][64] bf16 (transposed, zero-padded)
__global__ __launch_bounds__(256) void prep_wt(const float* __restrict__ fcw,
                                               unsigned short* __restrict__ wt) {
    int n = blockIdx.x * 256 + threadIdx.x;
    if (n >= VPAD) return;
    unsigned int packed[32];
    if (n < VOCAB) {
        #pragma unroll
        for (int k2 = 0; k2 < 32; ++k2) {
            unsigned int lo = f2bf(fcw[(size_t)(2*k2)   * VOCAB + n]);
            unsigned int hi = f2bf(fcw[(size_t)(2*k2+1) * VOCAB + n]);
            packed[k2] = lo | (hi << 16);
        }
    } else {
        #pragma unroll
        for (int k2 = 0; k2 < 32; ++k2) packed[k2] = 0u;
    }
    u32x4* dst = (u32x4*)(wt + (size_t)n * 64);
    #pragma unroll
    for (int i = 0; i < 8; ++i) {
        u32x4 v = { packed[4*i], packed[4*i+1], packed[4*i+2], packed[4*i+3] };
        dst[i] = v;
    }
}

// ---------------- embed gather + pos add -> h ; LN1 -> hn   (one wave per row)
__global__ __launch_bounds__(256) void embed_ln(const int* __restrict__ x,
                                                const float* __restrict__ ew,
                                                const float* __restrict__ pw,
                                                const float* __restrict__ g,
                                                const float* __restrict__ bb,
                                                float* __restrict__ h,
                                                float* __restrict__ hn) {
    int row = blockIdx.x * 4 + (threadIdx.x >> 6);
    int e   = threadIdx.x & 63;
    int tok = x[row];
    float v = ew[(size_t)tok * 64 + e] + pw[(size_t)(row & 255) * 64 + e];
    h[(size_t)row * 64 + e] = v;
    float s = v;
    #pragma unroll
    for (int m = 32; m >= 1; m >>= 1) s += __shfl_xor(s, m, 64);
    float mu = s * (1.f/64.f);
    float d  = v - mu;
    float s2 = d * d;
    #pragma unroll
    for (int m = 32; m >= 1; m >>= 1) s2 += __shfl_xor(s2, m, 64);
    float var = s2 * (1.f/64.f);
    hn[(size_t)row * 64 + e] = d * rsqrtf(var + LNEPS) * g[e] + bb[e];
}

// ---------------- Q,K,V GEMMs.  wave0->Q, wave1->K (stored transposed), wave2->V
__global__ __launch_bounds__(192) void qkv(const float* __restrict__ hn,
                                           const float* __restrict__ wq,
                                           const float* __restrict__ wk,
                                           const float* __restrict__ wv,
                                           float* __restrict__ q,
                                           float* __restrict__ kt,
                                           float* __restrict__ v) {
    int wave = threadIdx.x >> 6;     // 0..2
    int j    = threadIdx.x & 63;
    const float* W = (wave == 0) ? wq : ((wave == 1) ? wk : wv);
    int m0 = blockIdx.x * 16;
    for (int r = 0; r < 16; ++r) {
        int m = m0 + r;
        const float* hr = hn + (size_t)m * 64;   // uniform -> scalar loads
        float acc = 0.f;
        #pragma unroll
        for (int e = 0; e < 64; ++e) acc += hr[e] * W[e * 64 + j];
        if (wave == 0)      q[(size_t)m * 64 + j] = acc;
        else if (wave == 1) {
            int b = m >> 8, t = m & 255;
            kt[((size_t)b * 64 + j) * 256 + t] = acc;
        } else              v[(size_t)m * 64 + j] = acc;
    }
}

// ---------------- scores (QK^T/8, causal) + softmax -> P f32.  4 query rows per block.
__global__ __launch_bounds__(256) void attn_sm(const float* __restrict__ q,
                                               const float* __restrict__ kt,
                                               float* __restrict__ p) {
    int b   = blockIdx.y;            // 0..31
    int m4  = blockIdx.x;            // 0..63
    int key = threadIdx.x;           // 0..255
    int wave = key >> 6, lane = key & 63;
    const float* ktb = kt + (size_t)b * 64 * 256;
    const float* qb  = q  + ((size_t)b * 256 + m4 * 4) * 64;   // 4 rows, uniform
    float s0=0.f, s1=0.f, s2=0.f, s3=0.f;
    for (int e = 0; e < 64; ++e) {
        float kv = ktb[e * 256 + key];
        s0 += qb[e]       * kv;
        s1 += qb[64 + e]  * kv;
        s2 += qb[128 + e] * kv;
        s3 += qb[192 + e] * kv;
    }
    float sv[4] = { s0*0.125f, s1*0.125f, s2*0.125f, s3*0.125f };
    __shared__ float redm[4][4], reds[4][4];
    float pe[4];
    #pragma unroll
    for (int r = 0; r < 4; ++r) {
        int mrow = m4 * 4 + r;
        float xv = (key <= mrow) ? sv[r] : -1e30f;
        sv[r] = xv;
        float wm = xv;
        #pragma unroll
        for (int mm = 32; mm >= 1; mm >>= 1) wm = fmaxf(wm, __shfl_xor(wm, mm, 64));
        if (lane == 0) redm[wave][r] = wm;
    }
    __syncthreads();
    #pragma unroll
    for (int r = 0; r < 4; ++r) {
        float M = fmaxf(fmaxf(redm[0][r], redm[1][r]), fmaxf(redm[2][r], redm[3][r]));
        float e_ = expf(sv[r] - M);
        pe[r] = e_;
        float ws = e_;
        #pragma unroll
        for (int mm = 32; mm >= 1; mm >>= 1) ws += __shfl_xor(ws, mm, 64);
        if (lane == 0) reds[wave][r] = ws;
    }
    __syncthreads();
    float* pb = p + ((size_t)b * 256 + m4 * 4) * 256;
    #pragma unroll
    for (int r = 0; r < 4; ++r) {
        float S = reds[0][r] + reds[1][r] + reds[2][r] + reds[3][r];
        pb[r * 256 + key] = pe[r] / S;
    }
}

// ---------------- ctx = P@V ; h2 = h + ctx ; LNf -> hf bf16.  One wave per row.
__global__ __launch_bounds__(256) void ctx_lnf(const float* __restrict__ p,
                                               const float* __restrict__ v,
                                               const float* __restrict__ h,
                                               const float* __restrict__ g,
                                               const float* __restrict__ bb,
                                               unsigned short* __restrict__ hf) {
    int m = blockIdx.x * 4 + (threadIdx.x >> 6);
    int n = threadIdx.x & 63;
    int b = m >> 8, t = m & 255;
    const float* pr = p + ((size_t)b * 256 + t) * 256;   // uniform -> scalar loads
    const float* vb = v + (size_t)b * 256 * 64;
    float acc = 0.f;
    for (int key = 0; key <= t; ++key)
        acc += pr[key] * vb[key * 64 + n];
    float h2 = h[(size_t)m * 64 + n] + acc;
    float s = h2;
    #pragma unroll
    for (int mm = 32; mm >= 1; mm >>= 1) s += __shfl_xor(s, mm, 64);
    float mu = s * (1.f/64.f);
    float d  = h2 - mu;
    float s2 = d * d;
    #pragma unroll
    for (int mm = 32; mm >= 1; mm >>= 1) s2 += __shfl_xor(s2, mm, 64);
    float var = s2 * (1.f/64.f);
    hf[(size_t)m * 64 + n] = f2bf(d * rsqrtf(var + LNEPS) * g[n] + bb[n]);
}

// ---------------- logits = hf @ fc_w + fc_b  (bf16 MFMA, f32 out)
// R3's grid mapping (the best measured: per-XCD compact front + L2-hot wt),
// with the block slimmed for STORE DUTY CYCLE: 16 rows x 256 cols -> LDS
// 16.6KB -> 8 blocks/CU (R3 had 4). More resident blocks = compute/store
// phases of different blocks overlap instead of convoying, raising the
// store-issue duty toward the fill kernel's 100%. Swapped MFMA (A=wt, B=hf;
// verified R6): lane's c[0..3] = 4 consecutive vocab cols -> LDS fill is one
// ds_write_b128 per tile (shorter compute phase). Store phase: 256B runs,
// one barrier, stores never waited on.
__global__ __launch_bounds__(256) void final_gemm(const unsigned short* __restrict__ hf,
                                                  const unsigned short* __restrict__ wt,
                                                  const float* __restrict__ bias,
                                                  float* __restrict__ out) {
    int bid = blockIdx.x;                  // 0..101375 (= 8 XCD * 8 grp * 198 * 8)
    int xcd = bid & 7;
    int j   = bid >> 3;                    // 0..12671
    int g   = j / 1584;                    // 0..7   (8-band group within slab)
    int rj  = j - g * 1584;                // 0..1583
    int nb  = rj >> 3;                     // 0..197 (stripe; advances every 8)
    int mb  = xcd * 64 + g * 8 + (rj & 7); // band 0..511
    int m0  = mb * 16;
    int cb  = nb * BCOLS;                  // stripe base col

    int tid  = threadIdx.x;
    int wave = tid >> 6, lane = tid & 63;
    int l15 = lane & 15, lk = lane >> 4;

    __shared__ float lds[16][260];         // 16.6 KB; stride 260 (16B-aligned)

    // B-operand: token rows m0+l15 (loaded once)
    const bf16x8* hrow = (const bf16x8*)(hf + (size_t)(m0 + l15) * 64);
    bf16x8 hb0 = hrow[lk];       // k 0..31
    bf16x8 hb1 = hrow[4 + lk];   // k 32..63

    // compute phase: 4 tiles per wave (wave covers cols wave*64 .. +64)
    #pragma unroll
    for (int nt = 0; nt < 4; ++nt) {
        int lcol = wave * 64 + nt * 16;               // tile base in stripe
        const bf16x8* wrow = (const bf16x8*)(wt + (size_t)(cb + lcol + l15) * 64);
        f32x4 c = {0.f, 0.f, 0.f, 0.f};
        c = __builtin_amdgcn_mfma_f32_16x16x32_bf16(wrow[lk],     hb0, c, 0, 0, 0);
        c = __builtin_amdgcn_mfma_f32_16x16x32_bf16(wrow[4 + lk], hb1, c, 0, 0, 0);
        int bc = cb + lcol + lk * 4;                  // 4 consecutive vocab cols
        if (bc + 4 <= VOCAB) {
            c += *(const f32x4*)(bias + bc);
        } else {
            #pragma unroll
            for (int e = 0; e < 4; ++e)
                c[e] += (bc + e < VOCAB) ? bias[bc + e] : 0.f;
        }
        *(f32x4*)&lds[l15][lcol + lk * 4] = c;        // one b128 per tile
    }
    __syncthreads();

    // store phase: thread t -> token row t>>4; 4 x 256B contiguous runs
    int row = tid >> 4, cc = tid & 15;
    float* orow = out + (size_t)(m0 + row) * VOCAB + cb;
    const float* lrow = &lds[row][0];
    #pragma unroll
    for (int i = 0; i < 4; ++i) {
        int lcol = i * 64 + cc * 4;
        f32x4 vv = *(const f32x4*)(lrow + lcol);
        int cs = cb + lcol;
        if (cs + 4 <= VOCAB) {
            *(f32x4*)(orow + lcol) = vv;
        } else {
            #pragma unroll
            for (int e = 0; e < 4; ++e)
                if (cs + e < VOCAB) orow[lcol + e] = vv[e];
        }
    }
}

extern "C" void kernel_launch(void* const* d_in, const int* in_sizes, int n_in,
                              void* d_out, int out_size, void* d_ws, size_t ws_size,
                              hipStream_t stream) {
    const int*   x    = (const int*)  d_in[0];
    const float* ew   = (const float*)d_in[1];
    const float* pw   = (const float*)d_in[2];
    const float* ln1g = (const float*)d_in[3];
    const float* ln1b = (const float*)d_in[4];
    const float* wq   = (const float*)d_in[5];
    const float* wk   = (const float*)d_in[6];
    const float* wv   = (const float*)d_in[7];
    const float* lnfg = (const float*)d_in[8];
    const float* lnfb = (const float*)d_in[9];
    const float* fcw  = (const float*)d_in[10];
    const float* fcb  = (const float*)d_in[11];
    float* out = (float*)d_out;

    char* ws = (char*)d_ws;
    float*          h  = (float*)(ws + 0);                    //  0..2 MB
    float*          hn = (float*)(ws + (2u<<20));             //  2..4 MB (dead after qkv)
    unsigned short* hf = (unsigned short*)(ws + (2u<<20));    //  reuses hn slot (1 MB)
    float*          q  = (float*)(ws + (4u<<20));             //  4..6 MB
    float*          kt = (float*)(ws + (6u<<20));             //  6..8 MB
    float*          v  = (float*)(ws + (8u<<20));             //  8..10 MB
    float*          p  = (float*)(ws + (10u<<20));            // 10..18 MB
    unsigned short* wt = (unsigned short*)(ws + (18u<<20));   // 18..24.2 MB

    prep_wt  <<<dim3(VPAD / 256),  dim3(256), 0, stream>>>(fcw, wt);
    embed_ln <<<dim3(NROWS / 4),   dim3(256), 0, stream>>>(x, ew, pw, ln1g, ln1b, h, hn);
    qkv      <<<dim3(NROWS / 16),  dim3(192), 0, stream>>>(hn, wq, wk, wv, q, kt, v);
    attn_sm  <<<dim3(64, 32),      dim3(256), 0, stream>>>(q, kt, p);
    ctx_lnf  <<<dim3(NROWS / 4),   dim3(256), 0, stream>>>(p, v, h, lnfg, lnfb, hf);
    final_gemm<<<dim3(8 * 8 * NB * 8), dim3(256), 0, stream>>>(hf, wt, fcb, out);
}